// Round 1
// baseline (5964.032 us; speedup 1.0000x reference)
//
#include <hip/hip_runtime.h>
#include <cmath>

constexpr int B = 64, N_SP = 49, ENC = 1024, DEC = 512, EMB = 512, V = 10000;
constexpr int MS = 8, MW = 20;
constexpr int BW = B * MS;        // 512 batched word-rows (s*64+b)
constexpr int XDIM = EMB + ENC;   // 1536

// ---------------- mean over N ----------------
__global__ void mean_kernel(const float* __restrict__ sp, float* __restrict__ g) {
    int b = blockIdx.x;
    for (int c = threadIdx.x; c < ENC; c += blockDim.x) {
        float s = 0.f;
        for (int n = 0; n < N_SP; ++n) s += sp[(size_t)(b * N_SP + n) * ENC + c];
        g[b * ENC + c] = s * (1.0f / 49.0f);
    }
}

// ---------------- generic fp32 GEMM: C = A @ W^T + bias ----------------
// A [M,K] lda, W [N,K] ldw (row-major). ACT: 0 none, 1 tanh.
// SCATTER: 1 => fc output remap row=(s*MW+t)*64+b -> ((b*MS+s)*MW+t)
template <int BM, int BN, int BK, int TM, int TN, int ACT, int SCATTER>
__launch_bounds__(256)
__global__ void gemm_tn(const float* __restrict__ A, int lda,
                        const float* __restrict__ W, int ldw,
                        const float* __restrict__ bias,
                        float* __restrict__ C, int ldc,
                        int M, int N, int K) {
    __shared__ float As[BK][BM + 4];
    __shared__ float Ws[BK][BN + 4];
    const int tid = threadIdx.x;
    const int tx = tid % (BN / TN);
    const int ty = tid / (BN / TN);
    const int m0 = blockIdx.y * BM, n0 = blockIdx.x * BN;

    float acc[TM][TN];
#pragma unroll
    for (int i = 0; i < TM; ++i)
#pragma unroll
        for (int j = 0; j < TN; ++j) acc[i][j] = 0.f;

    constexpr int Q = BK / 4;            // float4 quads per tile row
    const int arow = tid / Q, akq = (tid % Q) * 4;   // BM*BK == 1024 == 256*4
    const int wrow = tid / Q, wkq = (tid % Q) * 4;

    for (int k0 = 0; k0 < K; k0 += BK) {
        float4 av = make_float4(0.f, 0.f, 0.f, 0.f);
        float4 wv = make_float4(0.f, 0.f, 0.f, 0.f);
        int gr = m0 + arow;
        if (gr < M) av = *reinterpret_cast<const float4*>(&A[(size_t)gr * lda + k0 + akq]);
        int gn = n0 + wrow;
        if (gn < N) wv = *reinterpret_cast<const float4*>(&W[(size_t)gn * ldw + k0 + wkq]);
        __syncthreads();
        As[akq + 0][arow] = av.x; As[akq + 1][arow] = av.y;
        As[akq + 2][arow] = av.z; As[akq + 3][arow] = av.w;
        Ws[wkq + 0][wrow] = wv.x; Ws[wkq + 1][wrow] = wv.y;
        Ws[wkq + 2][wrow] = wv.z; Ws[wkq + 3][wrow] = wv.w;
        __syncthreads();
#pragma unroll
        for (int kk = 0; kk < BK; ++kk) {
            float a[TM], w[TN];
#pragma unroll
            for (int i = 0; i < TM; ++i) a[i] = As[kk][ty * TM + i];
#pragma unroll
            for (int j = 0; j < TN; ++j) w[j] = Ws[kk][tx * TN + j];
#pragma unroll
            for (int i = 0; i < TM; ++i)
#pragma unroll
                for (int j = 0; j < TN; ++j) acc[i][j] += a[i] * w[j];
        }
        __syncthreads();
    }

#pragma unroll
    for (int i = 0; i < TM; ++i) {
        int r = m0 + ty * TM + i;
        if (r >= M) continue;
#pragma unroll
        for (int j = 0; j < TN; ++j) {
            int n = n0 + tx * TN + j;
            if (n >= N) continue;
            float v = acc[i][j] + bias[n];
            if (ACT == 1) v = tanhf(v);
            size_t off;
            if (SCATTER) {
                int bb = r & 63, tt = (r >> 6) % MW, ss = r / (64 * MW);
                off = (size_t)((bb * MS + ss) * MW + tt) * ldc + n;
            } else {
                off = (size_t)r * ldc + n;
            }
            C[off] = v;
        }
    }
}

// ---------------- GRU gate combine ----------------
// gi, gh: [M,1536]; hprev/hout: [M,512]. hout2 optional second copy.
// word_mode: row r=s*64+b maps to hout2 row (s*MW+t)*64+b.
__global__ void gru_combine(const float* __restrict__ gi, const float* __restrict__ gh,
                            const float* __restrict__ hprev, float* __restrict__ hout,
                            float* __restrict__ hout2, int M, int t, int word_mode) {
    int idx = blockIdx.x * blockDim.x + threadIdx.x;
    if (idx >= M * DEC) return;
    int r = idx / DEC, c = idx % DEC;
    size_t g0 = (size_t)r * 3 * DEC + c;
    float ir = gi[g0], iz = gi[g0 + DEC], in_ = gi[g0 + 2 * DEC];
    float hr = gh[g0], hz = gh[g0 + DEC], hn = gh[g0 + 2 * DEC];
    float rr = 1.f / (1.f + expf(-(ir + hr)));
    float zz = 1.f / (1.f + expf(-(iz + hz)));
    float nn = tanhf(in_ + rr * hn);
    float h = (1.f - zz) * nn + zz * hprev[(size_t)r * DEC + c];
    hout[(size_t)r * DEC + c] = h;
    if (hout2) {
        int r2 = word_mode ? (((r >> 6) * MW + t) << 6) + (r & 63) : r;
        hout2[(size_t)r2 * DEC + c] = h;
    }
}

// ---------------- attention + embedding gather -> x = [emb | ctx] ----------------
__launch_bounds__(256)
__global__ void attn_kernel(const float* __restrict__ sp, const float* __restrict__ att1,
                            const float* __restrict__ att2, const float* __restrict__ wfull,
                            const float* __restrict__ bfull, const float* __restrict__ embW,
                            const int* __restrict__ tw, float* __restrict__ x, int t) {
    int r = blockIdx.x;           // s*64+b
    int s = r >> 6, b = r & 63;
    __shared__ float a2[EMB];
    __shared__ float wf[EMB];
    __shared__ float alpha[64];
    int tid = threadIdx.x;
    for (int c = tid; c < EMB; c += 256) {
        a2[c] = att2[(size_t)r * EMB + c];
        wf[c] = wfull[c];
    }
    __syncthreads();
    int wave = tid >> 6, lane = tid & 63;
    for (int n = wave; n < N_SP; n += 4) {
        float acc = 0.f;
        const float* a1p = &att1[(size_t)(b * N_SP + n) * EMB];
        for (int c0 = 0; c0 < EMB; c0 += 64) {
            float v = a1p[c0 + lane] + a2[c0 + lane];
            v = fmaxf(v, 0.f);
            acc += v * wf[c0 + lane];
        }
        for (int m = 32; m; m >>= 1) acc += __shfl_xor(acc, m, 64);
        if (lane == 0) alpha[n] = acc + bfull[0];
    }
    __syncthreads();
    if (tid < 64) {
        float e = (tid < N_SP) ? alpha[tid] : -1e30f;
        float mx = e;
        for (int m = 32; m; m >>= 1) mx = fmaxf(mx, __shfl_xor(mx, m, 64));
        float p = (tid < N_SP) ? expf(e - mx) : 0.f;
        float sum = p;
        for (int m = 32; m; m >>= 1) sum += __shfl_xor(sum, m, 64);
        if (tid < N_SP) alpha[tid] = p / sum;
    }
    __syncthreads();
    for (int c = tid; c < ENC; c += 256) {
        float acc = 0.f;
        const float* spb = &sp[(size_t)b * N_SP * ENC + c];
#pragma unroll 7
        for (int n = 0; n < N_SP; ++n) acc += alpha[n] * spb[(size_t)n * ENC];
        x[(size_t)r * XDIM + EMB + c] = acc;
    }
    int word = (t == 0) ? 1 : tw[b * (MS * MW) + s * MW + (t - 1)];
    for (int c = tid; c < EMB; c += 256) x[(size_t)r * XDIM + c] = embW[(size_t)word * EMB + c];
}

// ---------------- policy / stop heads ----------------
__launch_bounds__(64)
__global__ void policy_kernel(const float* __restrict__ hs_all, const float* __restrict__ pW,
                              const float* __restrict__ pb, const float* __restrict__ sW,
                              const float* __restrict__ sb, float* __restrict__ out) {
    int r = blockIdx.x;       // s*64+b
    int s = r >> 6, b = r & 63;
    int lane = threadIdx.x;
    float acc[6] = {0.f, 0.f, 0.f, 0.f, 0.f, 0.f};
    for (int c = lane; c < DEC; c += 64) {
        float h = hs_all[(size_t)r * DEC + c];
#pragma unroll
        for (int j = 0; j < 5; ++j) acc[j] += h * pW[j * DEC + c];
        acc[5] += h * sW[c];
    }
#pragma unroll
    for (int j = 0; j < 6; ++j)
        for (int m = 32; m; m >>= 1) acc[j] += __shfl_xor(acc[j], m, 64);
    if (lane == 0) {
#pragma unroll
        for (int j = 0; j < 5; ++j) out[(b * MS + s) * 5 + j] = acc[j] + pb[j];
        out[B * MS * 5 + b * MS + s] = acc[5] + sb[0];
    }
}

extern "C" void kernel_launch(void* const* d_in, const int* in_sizes, int n_in,
                              void* d_out, int out_size, void* d_ws, size_t ws_size,
                              hipStream_t stream) {
    const float* sp   = (const float*)d_in[0];
    const int*   tw   = (const int*)d_in[1];
    const float* embW = (const float*)d_in[2];
    const float* sWih = (const float*)d_in[3];
    const float* sWhh = (const float*)d_in[4];
    const float* sbih = (const float*)d_in[5];
    const float* sbhh = (const float*)d_in[6];
    const float* pW   = (const float*)d_in[7];
    const float* pb   = (const float*)d_in[8];
    const float* stW  = (const float*)d_in[9];
    const float* stb  = (const float*)d_in[10];
    const float* aeW  = (const float*)d_in[11];
    const float* aeb  = (const float*)d_in[12];
    const float* adW  = (const float*)d_in[13];
    const float* adb  = (const float*)d_in[14];
    const float* afW  = (const float*)d_in[15];
    const float* afb  = (const float*)d_in[16];
    const float* wWih = (const float*)d_in[17];
    const float* wWhh = (const float*)d_in[18];
    const float* wbih = (const float*)d_in[19];
    const float* wbhh = (const float*)d_in[20];
    const float* fcW  = (const float*)d_in[21];
    const float* fcb  = (const float*)d_in[22];
    const float* iW   = (const float*)d_in[23];
    const float* ib   = (const float*)d_in[24];
    float* out = (float*)d_out;

    float* w = (float*)d_ws;
    float* g      = w; w += B * ENC;                    // [64,1024]
    float* att1   = w; w += (size_t)B * N_SP * EMB;     // [3136,512]
    float* h_s    = w; w += B * DEC;                    // [64,512]
    float* gi_s   = w; w += B * 3 * DEC;                // [64,1536]
    float* gh_s   = w; w += B * 3 * DEC;
    float* h_sall = w; w += MS * B * DEC;               // [512,512]
    float* xbuf   = w; w += (size_t)BW * XDIM;          // [512,1536]
    float* att2   = w; w += (size_t)BW * EMB;           // [512,512]
    float* gib    = w; w += (size_t)BW * 3 * DEC;       // [512,1536]
    float* ghb    = w; w += (size_t)BW * 3 * DEC;
    float* h_all  = w; w += (size_t)MS * MW * B * DEC;  // [10240,512]
    float* h_w    = w; w += (size_t)BW * DEC;           // [512,512]

    // Phase 0: precompute
    mean_kernel<<<B, 256, 0, stream>>>(sp, g);
    gemm_tn<64, 64, 16, 4, 4, 0, 0><<<dim3(512 / 64, (B * N_SP) / 64), 256, 0, stream>>>(
        sp, ENC, aeW, ENC, aeb, att1, EMB, B * N_SP, EMB, ENC);
    gemm_tn<64, 64, 16, 4, 4, 1, 0><<<dim3(512 / 64, 1), 256, 0, stream>>>(
        g, ENC, iW, ENC, ib, h_s, DEC, B, DEC, ENC);
    gemm_tn<64, 64, 16, 4, 4, 0, 0><<<dim3(1536 / 64, 1), 256, 0, stream>>>(
        g, ENC, sWih, ENC, sbih, gi_s, 3 * DEC, B, 3 * DEC, ENC);

    // Phase 1: sentence GRU (sequential, 8 steps)
    for (int i = 0; i < MS; ++i) {
        gemm_tn<64, 64, 16, 4, 4, 0, 0><<<dim3(1536 / 64, 1), 256, 0, stream>>>(
            h_s, DEC, sWhh, DEC, sbhh, gh_s, 3 * DEC, B, 3 * DEC, DEC);
        gru_combine<<<(B * DEC + 255) / 256, 256, 0, stream>>>(
            gi_s, gh_s, h_s, h_s, h_sall + (size_t)i * B * DEC, B, 0, 0);
    }
    policy_kernel<<<BW, 64, 0, stream>>>(h_sall, pW, pb, stW, stb, out);
    hipMemcpyAsync(h_w, h_sall, (size_t)BW * DEC * sizeof(float),
                   hipMemcpyDeviceToDevice, stream);

    // Phase 2: word GRU, 8 sentences batched (M=512), 20 sequential steps
    for (int t = 0; t < MW; ++t) {
        gemm_tn<64, 64, 16, 4, 4, 0, 0><<<dim3(512 / 64, 512 / 64), 256, 0, stream>>>(
            h_w, DEC, adW, DEC, adb, att2, EMB, BW, EMB, DEC);
        attn_kernel<<<BW, 256, 0, stream>>>(sp, att1, att2, afW, afb, embW, tw, xbuf, t);
        gemm_tn<64, 64, 16, 4, 4, 0, 0><<<dim3(1536 / 64, 512 / 64), 256, 0, stream>>>(
            xbuf, XDIM, wWih, XDIM, wbih, gib, 3 * DEC, BW, 3 * DEC, XDIM);
        gemm_tn<64, 64, 16, 4, 4, 0, 0><<<dim3(1536 / 64, 512 / 64), 256, 0, stream>>>(
            h_w, DEC, wWhh, DEC, wbhh, ghb, 3 * DEC, BW, 3 * DEC, DEC);
        gru_combine<<<(BW * DEC + 255) / 256, 256, 0, stream>>>(
            gib, ghb, h_w, h_w, h_all, BW, t, 1);
    }

    // Phase 3: big output head with scatter to [b,s,t,v]
    gemm_tn<128, 128, 8, 8, 8, 0, 1><<<dim3((V + 127) / 128, (MS * MW * B) / 128), 256, 0, stream>>>(
        h_all, DEC, fcW, DEC, fcb, out + B * MS * 5 + B * MS, V, MS * MW * B, V, DEC);
}